// Round 11
// baseline (412.190 us; speedup 1.0000x reference)
//
#include <hip/hip_runtime.h>
#include <hip/hip_bf16.h>
#include <cmath>

#define BT 8192      // B*T tokens
#define DD 1024      // model dim
#define EE 8         // experts
#define HH 2048      // hidden

typedef __attribute__((ext_vector_type(8))) short bf16x8;
typedef __attribute__((ext_vector_type(4))) float f32x4;

__device__ __forceinline__ unsigned short f2bf(float f) {
    union { float f; unsigned u; } v; v.f = f;
    unsigned r = v.u + 0x7FFFu + ((v.u >> 16) & 1u);   // RNE
    return (unsigned short)(r >> 16);
}

__device__ __forceinline__ float bf2f(unsigned short s) {
    union { unsigned u; float f; } v; v.u = ((unsigned)s) << 16;
    return v.f;
}

// tanh-form GELU via sigmoid: max |diff vs exact erf-GELU| ~5e-4
__device__ __forceinline__ float gelu_fast(float x) {
    float z = x * (1.5957691216f + 0.071354816f * x * x);
    return x / (1.f + __expf(-z));
}

// async global->LDS, 16B per lane; LDS dest = wave-uniform base + lane*16
__device__ __forceinline__ void gload16(const void* g, void* l) {
    __builtin_amdgcn_global_load_lds(
        (const __attribute__((address_space(1))) void*)g,
        (__attribute__((address_space(3))) void*)l, 16, 0, 0);
}

// ---------------- fused prep: gating (+x->bf16) for bid<2048, W transposes otherwise ----------------
__global__ __launch_bounds__(256) void prep_kernel(
        const float* __restrict__ x, const float* __restrict__ Wg, const float* __restrict__ bg,
        const float* __restrict__ W1, const float* __restrict__ W2,
        int* __restrict__ tk_pack, float* __restrict__ tk_w, float* __restrict__ ssq,
        unsigned short* __restrict__ xbf, unsigned short* __restrict__ W1T,
        unsigned short* __restrict__ W2T) {
    __shared__ unsigned short tl[64][66];
    int bid = blockIdx.x;
    int tid = threadIdx.x;

    if (bid < BT / 4) {
        int lane = tid & 63;
        int wid  = tid >> 6;
        int t = bid * 4 + wid;
        const float* xr = x + (size_t)t * DD;
        unsigned* xbr = (unsigned*)(xbf + (size_t)t * DD);
        float acc[EE];
#pragma unroll
        for (int e = 0; e < EE; ++e) acc[e] = 0.f;
        for (int d = lane * 2; d < DD; d += 128) {
            float2 xv = *(const float2*)&xr[d];
            xbr[d >> 1] = (unsigned)f2bf(xv.x) | ((unsigned)f2bf(xv.y) << 16);
            const float* wr = Wg + d * EE;
#pragma unroll
            for (int e = 0; e < EE; ++e) acc[e] += xv.x * wr[e] + xv.y * wr[e + EE];
        }
#pragma unroll
        for (int off = 32; off; off >>= 1)
#pragma unroll
            for (int e = 0; e < EE; ++e) acc[e] += __shfl_xor(acc[e], off, 64);

        if (lane == 0) {
            float p[EE]; float m = -1e30f;
#pragma unroll
            for (int e = 0; e < EE; ++e) { p[e] = acc[e] + bg[e]; m = fmaxf(m, p[e]); }
            float s = 0.f;
#pragma unroll
            for (int e = 0; e < EE; ++e) { p[e] = expf(p[e] - m); s += p[e]; }
            float inv = 1.f / s, q = 0.f;
#pragma unroll
            for (int e = 0; e < EE; ++e) { p[e] = 0.99f * p[e] * inv + 0.00125f; q += p[e] * p[e]; }
            ssq[t] = q;
            int i1 = 0;
#pragma unroll
            for (int e = 1; e < EE; ++e) if (p[e] > p[i1]) i1 = e;    // lowest idx on tie
            int i2 = (i1 == 0) ? 1 : 0;
#pragma unroll
            for (int e = 0; e < EE; ++e) if (e != i1 && p[e] > p[i2]) i2 = e;
            tk_pack[t] = i1 | (i2 << 4);
            tk_w[t] = p[i1] / (p[i1] + p[i2]);         // w2 = 1 - w1
        }
        return;
    }

    int bid2 = bid - BT / 4;
    const float* in; unsigned short* out; int R, C, r0, c0, e;
    if (bid2 < 4096) {           // W1 [8][1024][2048] -> [8][2048][1024]
        in = W1; out = W1T; R = DD; C = HH;
        e = bid2 & 7; int t = bid2 >> 3; c0 = (t & 31) * 64; r0 = (t >> 5) * 64;
    } else {                     // W2 [8][2048][1024] -> [8][1024][2048]
        bid2 -= 4096;
        in = W2; out = W2T; R = HH; C = DD;
        e = bid2 & 7; int t = bid2 >> 3; c0 = (t & 15) * 64; r0 = (t >> 4) * 64;
    }
    int ci = (tid & 31) * 2;
    int ri = tid >> 5;
    const float* src = in + ((size_t)e * R + r0) * C + c0;
#pragma unroll
    for (int j = 0; j < 8; ++j) {
        int r = ri + j * 8;
        float2 v = *(const float2*)&src[(size_t)r * C + ci];
        tl[ci][r] = f2bf(v.x); tl[ci + 1][r] = f2bf(v.y);
    }
    __syncthreads();
    int r2 = (tid & 15) * 4, c2 = tid >> 4;
    unsigned short* dst = out + ((size_t)e * C + c0) * R + r0;
#pragma unroll
    for (int j = 0; j < 4; ++j) {
        int c = c2 + j * 16;
        ushort4 v = { tl[c][r2], tl[c][r2 + 1], tl[c][r2 + 2], tl[c][r2 + 3] };
        *(ushort4*)&dst[(size_t)c * R + r2] = v;
    }
}

// ---------------- scatter + offsets (last-block): LDS histogram, 8 global atomics/block ----------------
__global__ __launch_bounds__(256) void scatter_kernel(const int* __restrict__ tk_pack,
                                                      int* __restrict__ counts,
                                                      int* __restrict__ done,
                                                      int* __restrict__ tok_list,
                                                      int* __restrict__ tk_pos,
                                                      int* __restrict__ offs) {
    __shared__ int lcnt[EE];
    __shared__ int gbase[EE];
    int tid = threadIdx.x;
    int t = blockIdx.x * 256 + tid;
    if (tid < EE) lcnt[tid] = 0;
    __syncthreads();
    int pk = tk_pack[t];
    int i1 = pk & 15, i2 = pk >> 4;
    int p1 = atomicAdd(&lcnt[i1], 1);
    int p2 = atomicAdd(&lcnt[i2], 1);
    __syncthreads();
    if (tid < EE) gbase[tid] = atomicAdd(&counts[tid], lcnt[tid]);
    __syncthreads();
    int q1 = gbase[i1] + p1, q2 = gbase[i2] + p2;
    tok_list[i1 * BT + q1] = t;
    tok_list[i2 * BT + q2] = t;
    tk_pos[t] = q1 | (q2 << 16);
    if (tid == 0) {
        __threadfence();
        if (atomicAdd(done, 1) == (int)gridDim.x - 1) {
            int a = 0;
#pragma unroll
            for (int e = 0; e < EE; ++e) { offs[e] = a; a += atomicAdd(&counts[e], 0); }
            offs[EE] = a;
        }
    }
}

// =====================================================================================
// 128x256 tile, 4 waves of 128x64 (acc 8x4 = 128 VGPR), BK=32, single-buffer 24KB LDS,
// r5-proven sync/swizzle skeleton. LDS traffic 34 KB/MFLOP (vs 46 at 64x64 wave tiles).
// =====================================================================================
template<int KDIM, int NDIM, bool DOGELU, bool GATHER>
__device__ __forceinline__ void gemm_tile(
        unsigned short* lds,
        const unsigned short* __restrict__ Amat, const unsigned short* __restrict__ WT,
        const float* __restrict__ bias, int e, int m0, int n0, int cnt, int base,
        const int* __restrict__ tok_list, unsigned short* __restrict__ Out, int tid) {
    int l = tid & 63, w = tid >> 6;

    // staging: A rows w*32+(l>>2)+{0,16}; B nrows w*64+(l>>2)+{0,16,32,48}; src granule-swizzled
    int g = (l & 3) ^ ((l >> 3) & 3);
    int ra0 = m0 + w * 32 + (l >> 2);      if (ra0 >= cnt) ra0 = cnt - 1;
    int ra1 = m0 + w * 32 + (l >> 2) + 16; if (ra1 >= cnt) ra1 = cnt - 1;
    size_t gr0 = GATHER ? (size_t)tok_list[e * BT + ra0] : (size_t)(base + ra0);
    size_t gr1 = GATHER ? (size_t)tok_list[e * BT + ra1] : (size_t)(base + ra1);
    const unsigned short* pa0 = Amat + gr0 * KDIM + g * 8;
    const unsigned short* pa1 = Amat + gr1 * KDIM + g * 8;
    const unsigned short* pb[4];
#pragma unroll
    for (int i = 0; i < 4; ++i)
        pb[i] = WT + ((size_t)e * NDIM + n0 + w * 64 + i * 16 + (l >> 2)) * KDIM + g * 8;

    int slot = (l >> 4) ^ ((l >> 1) & 3);
    int rdA = (l & 15) * 32 + slot * 8;                    // + fm*512
    int rdB = 4096 + (w * 64 + (l & 15)) * 32 + slot * 8;  // + fn*512

    f32x4 acc[8][4];
#pragma unroll
    for (int i = 0; i < 8; ++i)
#pragma unroll
        for (int q = 0; q < 4; ++q) acc[i][q] = (f32x4){0.f, 0.f, 0.f, 0.f};

    for (int kt = 0; kt < KDIM / 32; ++kt) {
        int k0 = kt * 32;
        __syncthreads();                   // prev reads done (WAR)
        gload16(pa0 + k0, &lds[w * 1024]);
        gload16(pa1 + k0, &lds[w * 1024 + 512]);
#pragma unroll
        for (int i = 0; i < 4; ++i)
            gload16(pb[i] + k0, &lds[4096 + w * 2048 + i * 512]);
        __syncthreads();                   // drains vmcnt: tile resident

        bf16x8 af[8], bf[4];
#pragma unroll
        for (int f = 0; f < 8; ++f) af[f] = *(const bf16x8*)&lds[rdA + f * 512];
#pragma unroll
        for (int f = 0; f < 4; ++f) bf[f] = *(const bf16x8*)&lds[rdB + f * 512];
#pragma unroll
        for (int fm = 0; fm < 8; ++fm)
#pragma unroll
            for (int fn = 0; fn < 4; ++fn)   // swapped: D[n][token]
                acc[fm][fn] = __builtin_amdgcn_mfma_f32_16x16x32_bf16(bf[fn], af[fm], acc[fm][fn], 0, 0, 0);
    }

    const float* be = bias + e * NDIM;
#pragma unroll
    for (int fm = 0; fm < 8; ++fm) {
        int r = m0 + fm * 16 + (l & 15);
        if (r >= cnt) continue;
        unsigned short* orow = Out + (size_t)(base + r) * NDIM;
#pragma unroll
        for (int fn = 0; fn < 4; ++fn) {
            int n = n0 + w * 64 + fn * 16 + (l >> 4) * 4;
            float4 bb4 = *(const float4*)&be[n];
            f32x4 a = acc[fm][fn];
            float v0 = a[0] + bb4.x, v1 = a[1] + bb4.y;
            float v2 = a[2] + bb4.z, v3 = a[3] + bb4.w;
            if (DOGELU) {
                v0 = gelu_fast(v0); v1 = gelu_fast(v1);
                v2 = gelu_fast(v2); v3 = gelu_fast(v3);
            }
            ushort4 pk = { f2bf(v0), f2bf(v1), f2bf(v2), f2bf(v3) };
            *(ushort4*)&orow[n] = pk;
        }
    }
}

// ---------------- fused persistent GEMM: per-expert work queues, gemm1 then gemm2 ----------------
// item < n1: gemm1 (mt=item>>3, nt=item&7). else gemm2 (mt, nt of 4), gated on done1[e][mt]==8.
__global__ __launch_bounds__(256, 2) void moe_gemm_fused(
        const unsigned short* __restrict__ xbf, const unsigned short* __restrict__ W1T,
        const float* __restrict__ b1, const unsigned short* __restrict__ W2T,
        const float* __restrict__ b2, const int* __restrict__ counts,
        const int* __restrict__ offs, const int* __restrict__ tok_list,
        int* __restrict__ claim, int* __restrict__ done1,
        unsigned short* __restrict__ hbuf, unsigned short* __restrict__ ybuf) {
    __shared__ __align__(16) unsigned short lds[12288];
    __shared__ int s_item;
    int e = blockIdx.x & 7;                 // queue = expert -> XCD locality (perf-only)
    int cnt = counts[e];
    int base = offs[e];
    int mts = (cnt + 127) >> 7;
    int n1 = mts * 8, n2 = mts * 4;
    int tid = threadIdx.x;

    for (;;) {
        __syncthreads();
        if (tid == 0) s_item = atomicAdd(&claim[e], 1);
        __syncthreads();
        int it = s_item;
        if (it >= n1 + n2) return;

        if (it < n1) {
            gemm_tile<DD, HH, true, true>(lds, xbf, W1T, b1, e, (it >> 3) * 128,
                                          (it & 7) * 256, cnt, base, tok_list, hbuf, tid);
            __syncthreads();               // all waves' stores drained (vmcnt0 at barrier)
            if (tid == 0) {
                __threadfence();
                __hip_atomic_fetch_add(&done1[(e << 6) + (it >> 3)], 1,
                                       __ATOMIC_RELEASE, __HIP_MEMORY_SCOPE_AGENT);
            }
        } else {
            int i2 = it - n1;
            int mt = i2 >> 2;
            if (tid == 0) {                // deps claimed earlier in-queue -> running/done
                while (__hip_atomic_load(&done1[(e << 6) + mt],
                                         __ATOMIC_ACQUIRE, __HIP_MEMORY_SCOPE_AGENT) < 8)
                    __builtin_amdgcn_s_sleep(2);
            }
            __syncthreads();
            gemm_tile<HH, DD, false, false>(lds, hbuf, W2T, b2, e, mt * 128,
                                            (i2 & 3) * 256, cnt, base, tok_list, ybuf, tid);
        }
    }
}

// ---------------- plain wrappers (fallback when ws too small for fused layout) ----------------
template<int KDIM, int NDIM, bool DOGELU, bool GATHER>
__global__ __launch_bounds__(256, 2) void moe_gemm_plain(
        const unsigned short* __restrict__ Amat, const unsigned short* __restrict__ WT,
        const float* __restrict__ bias, const int* __restrict__ counts,
        const int* __restrict__ offs, const int* __restrict__ tok_list,
        unsigned short* __restrict__ Out) {
    __shared__ __align__(16) unsigned short lds[12288];
    constexpr int NNT = NDIM / 256;
    int e = blockIdx.x & 7;
    int j = blockIdx.x >> 3;
    int nt = j % NNT, mt = j / NNT;
    int cnt = counts[e];
    if (mt * 128 >= cnt) return;
    gemm_tile<KDIM, NDIM, DOGELU, GATHER>(lds, Amat, WT, bias, e, mt * 128, nt * 256,
                                          cnt, offs[e], tok_list, Out, threadIdx.x);
}

// ---------------- combine (+ fused aux): out[t] = w1*y[row1] + (1-w1)*y[row2] ----------------
__global__ __launch_bounds__(256) void combine_kernel(
        const unsigned short* __restrict__ ybuf, const int* __restrict__ offs,
        const int* __restrict__ tk_pack, const float* __restrict__ tk_w,
        const int* __restrict__ tk_pos, const float* __restrict__ ssq,
        float* __restrict__ out) {
    if (blockIdx.x == BT / 2) {
        __shared__ float red[4];
        float s = 0.f;
        for (int i = threadIdx.x; i < BT; i += 256) s += ssq[i];
#pragma unroll
        for (int off = 32; off; off >>= 1) s += __shfl_xor(s, off, 64);
        if ((threadIdx.x & 63) == 0) red[threadIdx.x >> 6] = s;
        __syncthreads();
        if (threadIdx.x == 0)
            out[(size_t)BT * DD] = (red[0] + red[1] + red[2] + red[3]) * (float)EE / (float)BT;
        return;
    }
    int tid = threadIdx.x;
    int t  = blockIdx.x * 2 + (tid >> 7);
    int lt = tid & 127;
    int pk  = tk_pack[t];
    int pos = tk_pos[t];
    float w1 = tk_w[t], w2 = 1.f - w1;
    int r1 = offs[pk & 15] + (pos & 0xffff);
    int r2 = offs[pk >> 4] + (pos >> 16);
    ushort4 a0 = ((const ushort4*)(ybuf + (size_t)r1 * DD))[lt * 2];
    ushort4 a1 = ((const ushort4*)(ybuf + (size_t)r1 * DD))[lt * 2 + 1];
    ushort4 b0 = ((const ushort4*)(ybuf + (size_t)r2 * DD))[lt * 2];
    ushort4 b1 = ((const ushort4*)(ybuf + (size_t)r2 * DD))[lt * 2 + 1];
    float4 o0 = { w1 * bf2f(a0.x) + w2 * bf2f(b0.x), w1 * bf2f(a0.y) + w2 * bf2f(b0.y),
                  w1 * bf2f(a0.z) + w2 * bf2f(b0.z), w1 * bf2f(a0.w) + w2 * bf2f(b0.w) };
    float4 o1 = { w1 * bf2f(a1.x) + w2 * bf2f(b1.x), w1 * bf2f(a1.y) + w2 * bf2f(b1.y),
                  w1 * bf2f(a1.z) + w2 * bf2f(b1.z), w1 * bf2f(a1.w) + w2 * bf2f(b1.w) };
    float4* orow = (float4*)(out + (size_t)t * DD);
    orow[lt * 2]     = o0;
    orow[lt * 2 + 1] = o1;
}

extern "C" void kernel_launch(void* const* d_in, const int* in_sizes, int n_in,
                              void* d_out, int out_size, void* d_ws, size_t ws_size,
                              hipStream_t stream) {
    const float* x  = (const float*)d_in[0];
    const float* Wg = (const float*)d_in[1];
    const float* bg = (const float*)d_in[2];
    const float* W1 = (const float*)d_in[3];
    const float* b1 = (const float*)d_in[4];
    const float* W2 = (const float*)d_in[5];
    const float* b2 = (const float*)d_in[6];
    float* out = (float*)d_out;

    char* wsb = (char*)d_ws;
    int*   counts  = (int*)wsb;                         // 0 .. 32
    int*   sdone   = (int*)(wsb + 32);                  // 32 .. 36
    int*   claim   = (int*)(wsb + 64);                  // 64 .. 96
    int*   offs    = (int*)(wsb + 128);                 // 128 .. 164
    int*   done1   = (int*)(wsb + 256);                 // 256 .. 2304 (8*64 ints)
    int*   tok     = (int*)(wsb + 4096);                // -> 266240
    float* ssq     = (float*)(wsb + 266240);            // -> 299008
    int*   tk_pack = (int*)(wsb + 299008);              // -> 331776
    float* tk_w    = (float*)(wsb + 331776);            // -> 364544
    int*   tk_pos  = (int*)(wsb + 364544);              // -> 397312
    unsigned short* xbf  = (unsigned short*)(wsb + 397312);      // 16 MB -> 17174528
    unsigned short* W1T  = (unsigned short*)(wsb + 17174528);    // 32 MB -> 50728960
    unsigned short* W2T  = (unsigned short*)(wsb + 50728960);    // 32 MB -> 84283392
    unsigned short* hbuf = (unsigned short*)(wsb + 84283392);    // 64 MB -> 151392256

    bool fused = ws_size >= 184946688ull;   // ybuf must coexist with xbf/W1T in fused mode
    unsigned short* ybuf = fused ? (unsigned short*)(wsb + 151392256)
                                 : (unsigned short*)(wsb + 397312);  // overlay (dead after gemm1)

    hipMemsetAsync(wsb, 0, 2304, stream);   // counts + sdone + claim + done1

    prep_kernel<<<BT / 4 + 8192, 256, 0, stream>>>(x, Wg, bg, W1, W2,
                                                   tk_pack, tk_w, ssq, xbf, W1T, W2T);
    scatter_kernel<<<BT / 256, 256, 0, stream>>>(tk_pack, counts, sdone, tok, tk_pos, offs);
    if (fused) {
        moe_gemm_fused<<<8 * 768, 256, 0, stream>>>(xbf, W1T, b1, W2T, b2, counts, offs,
                                                    tok, claim, done1, hbuf, ybuf);
    } else {
        moe_gemm_plain<DD, HH, true, true><<<8 * 8 * (BT / 128), 256, 0, stream>>>(
            xbf, W1T, b1, counts, offs, tok, hbuf);
        moe_gemm_plain<HH, DD, false, false><<<8 * 4 * (BT / 128), 256, 0, stream>>>(
            hbuf, W2T, b2, counts, offs, tok, ybuf);
    }
    combine_kernel<<<BT / 2 + 1, 256, 0, stream>>>(ybuf, offs, tk_pack, tk_w, tk_pos, ssq, out);
}

// Round 12
// 324.515 us; speedup vs baseline: 1.2702x; 1.2702x over previous
//
#include <hip/hip_runtime.h>
#include <hip/hip_bf16.h>
#include <cmath>

#define BT 8192      // B*T tokens
#define DD 1024      // model dim
#define EE 8         // experts
#define HH 2048      // hidden

typedef __attribute__((ext_vector_type(8))) short bf16x8;
typedef __attribute__((ext_vector_type(4))) float f32x4;

__device__ __forceinline__ unsigned short f2bf(float f) {
    union { float f; unsigned u; } v; v.f = f;
    unsigned r = v.u + 0x7FFFu + ((v.u >> 16) & 1u);   // RNE
    return (unsigned short)(r >> 16);
}

__device__ __forceinline__ float bf2f(unsigned short s) {
    union { unsigned u; float f; } v; v.u = ((unsigned)s) << 16;
    return v.f;
}

// tanh-form GELU via sigmoid: max |diff vs exact erf-GELU| ~5e-4
__device__ __forceinline__ float gelu_fast(float x) {
    float z = x * (1.5957691216f + 0.071354816f * x * x);
    return x / (1.f + __expf(-z));
}

// async global->LDS, 16B per lane; LDS dest = wave-uniform base + lane*16
__device__ __forceinline__ void gload16(const void* g, void* l) {
    __builtin_amdgcn_global_load_lds(
        (const __attribute__((address_space(1))) void*)g,
        (__attribute__((address_space(3))) void*)l, 16, 0, 0);
}

// ---------------- fused prep: gating (+x->bf16) for bid<2048, W transposes otherwise ----------------
__global__ __launch_bounds__(256) void prep_kernel(
        const float* __restrict__ x, const float* __restrict__ Wg, const float* __restrict__ bg,
        const float* __restrict__ W1, const float* __restrict__ W2,
        int* __restrict__ tk_pack, float* __restrict__ tk_w, float* __restrict__ ssq,
        unsigned short* __restrict__ xbf, unsigned short* __restrict__ W1T,
        unsigned short* __restrict__ W2T) {
    __shared__ unsigned short tl[64][66];
    int bid = blockIdx.x;
    int tid = threadIdx.x;

    if (bid < BT / 4) {
        int lane = tid & 63;
        int wid  = tid >> 6;
        int t = bid * 4 + wid;
        const float* xr = x + (size_t)t * DD;
        unsigned* xbr = (unsigned*)(xbf + (size_t)t * DD);
        float acc[EE];
#pragma unroll
        for (int e = 0; e < EE; ++e) acc[e] = 0.f;
        for (int d = lane * 2; d < DD; d += 128) {
            float2 xv = *(const float2*)&xr[d];
            xbr[d >> 1] = (unsigned)f2bf(xv.x) | ((unsigned)f2bf(xv.y) << 16);
            const float* wr = Wg + d * EE;
#pragma unroll
            for (int e = 0; e < EE; ++e) acc[e] += xv.x * wr[e] + xv.y * wr[e + EE];
        }
#pragma unroll
        for (int off = 32; off; off >>= 1)
#pragma unroll
            for (int e = 0; e < EE; ++e) acc[e] += __shfl_xor(acc[e], off, 64);

        if (lane == 0) {
            float p[EE]; float m = -1e30f;
#pragma unroll
            for (int e = 0; e < EE; ++e) { p[e] = acc[e] + bg[e]; m = fmaxf(m, p[e]); }
            float s = 0.f;
#pragma unroll
            for (int e = 0; e < EE; ++e) { p[e] = expf(p[e] - m); s += p[e]; }
            float inv = 1.f / s, q = 0.f;
#pragma unroll
            for (int e = 0; e < EE; ++e) { p[e] = 0.99f * p[e] * inv + 0.00125f; q += p[e] * p[e]; }
            ssq[t] = q;
            int i1 = 0;
#pragma unroll
            for (int e = 1; e < EE; ++e) if (p[e] > p[i1]) i1 = e;    // lowest idx on tie
            int i2 = (i1 == 0) ? 1 : 0;
#pragma unroll
            for (int e = 0; e < EE; ++e) if (e != i1 && p[e] > p[i2]) i2 = e;
            tk_pack[t] = i1 | (i2 << 4);
            tk_w[t] = p[i1] / (p[i1] + p[i2]);         // w2 = 1 - w1
        }
        return;
    }

    int bid2 = bid - BT / 4;
    const float* in; unsigned short* out; int R, C, r0, c0, e;
    if (bid2 < 4096) {           // W1 [8][1024][2048] -> [8][2048][1024]
        in = W1; out = W1T; R = DD; C = HH;
        e = bid2 & 7; int t = bid2 >> 3; c0 = (t & 31) * 64; r0 = (t >> 5) * 64;
    } else {                     // W2 [8][2048][1024] -> [8][1024][2048]
        bid2 -= 4096;
        in = W2; out = W2T; R = HH; C = DD;
        e = bid2 & 7; int t = bid2 >> 3; c0 = (t & 15) * 64; r0 = (t >> 4) * 64;
    }
    int ci = (tid & 31) * 2;
    int ri = tid >> 5;
    const float* src = in + ((size_t)e * R + r0) * C + c0;
#pragma unroll
    for (int j = 0; j < 8; ++j) {
        int r = ri + j * 8;
        float2 v = *(const float2*)&src[(size_t)r * C + ci];
        tl[ci][r] = f2bf(v.x); tl[ci + 1][r] = f2bf(v.y);
    }
    __syncthreads();
    int r2 = (tid & 15) * 4, c2 = tid >> 4;
    unsigned short* dst = out + ((size_t)e * C + c0) * R + r0;
#pragma unroll
    for (int j = 0; j < 4; ++j) {
        int c = c2 + j * 16;
        ushort4 v = { tl[c][r2], tl[c][r2 + 1], tl[c][r2 + 2], tl[c][r2 + 3] };
        *(ushort4*)&dst[(size_t)c * R + r2] = v;
    }
}

// ---------------- scatter + offsets (last-block): LDS histogram, 8 global atomics/block ----------------
__global__ __launch_bounds__(256) void scatter_kernel(const int* __restrict__ tk_pack,
                                                      int* __restrict__ counts,
                                                      int* __restrict__ done,
                                                      int* __restrict__ tok_list,
                                                      int* __restrict__ tk_pos,
                                                      int* __restrict__ offs) {
    __shared__ int lcnt[EE];
    __shared__ int gbase[EE];
    int tid = threadIdx.x;
    int t = blockIdx.x * 256 + tid;
    if (tid < EE) lcnt[tid] = 0;
    __syncthreads();
    int pk = tk_pack[t];
    int i1 = pk & 15, i2 = pk >> 4;
    int p1 = atomicAdd(&lcnt[i1], 1);
    int p2 = atomicAdd(&lcnt[i2], 1);
    __syncthreads();
    if (tid < EE) gbase[tid] = atomicAdd(&counts[tid], lcnt[tid]);
    __syncthreads();
    int q1 = gbase[i1] + p1, q2 = gbase[i2] + p2;
    tok_list[i1 * BT + q1] = t;
    tok_list[i2 * BT + q2] = t;
    tk_pos[t] = q1 | (q2 << 16);
    if (tid == 0) {
        __threadfence();
        if (atomicAdd(done, 1) == (int)gridDim.x - 1) {
            int a = 0;
#pragma unroll
            for (int e = 0; e < EE; ++e) { offs[e] = a; a += atomicAdd(&counts[e], 0); }
            offs[EE] = a;
        }
    }
}

// =====================================================================================
// grouped GEMM: 128x256 block, 4 waves each owning 128x64 (acc 8x4), BK=32,
// single-buffer 24KB LDS, 2 barriers/K-step, r5-proven granule swizzle.
// LDS reads 23 KB/MFLOP (vs 31 at 64x64 waves); MFMA/wave/K-step (154cy) > ds_read (144cy).
// =====================================================================================
template<int KDIM, int NDIM, bool DOGELU, bool GATHER>
__global__ __launch_bounds__(256, 2) void moe_gemm_kernel(
        const unsigned short* __restrict__ Amat, const unsigned short* __restrict__ WT,
        const float* __restrict__ bias, const int* __restrict__ counts,
        const int* __restrict__ offs, const int* __restrict__ tok_list,
        unsigned short* __restrict__ Out) {
    constexpr int NNT = NDIM / 256;
    int e = blockIdx.x & 7;                 // expert -> XCD pin
    int j = blockIdx.x >> 3;
    int nt = j % NNT, mt = j / NNT;
    int cnt = counts[e];
    int m0 = mt * 128;
    if (m0 >= cnt) return;
    int n0 = nt * 256;
    int base = offs[e];

    // A: 128 rows x 32 k @0 (4096 shorts); B: 256 nrows x 32 k @4096 (8192 shorts). 24KB.
    __shared__ __align__(16) unsigned short lds[12288];

    int tid = threadIdx.x, l = tid & 63, w = tid >> 6;

    // staging: src granule-swizzled, LDS linear (both-sides involution with read slot)
    int g = (l & 3) ^ ((l >> 3) & 3);
    int ra0 = m0 + w * 32 + (l >> 2);      if (ra0 >= cnt) ra0 = cnt - 1;
    int ra1 = m0 + w * 32 + (l >> 2) + 16; if (ra1 >= cnt) ra1 = cnt - 1;
    size_t gr0 = GATHER ? (size_t)tok_list[e * BT + ra0] : (size_t)(base + ra0);
    size_t gr1 = GATHER ? (size_t)tok_list[e * BT + ra1] : (size_t)(base + ra1);
    const unsigned short* pa0 = Amat + gr0 * KDIM + g * 8;
    const unsigned short* pa1 = Amat + gr1 * KDIM + g * 8;
    const unsigned short* pb[4];
#pragma unroll
    for (int i = 0; i < 4; ++i)
        pb[i] = WT + ((size_t)e * NDIM + n0 + w * 64 + i * 16 + (l >> 2)) * KDIM + g * 8;

    int slot = (l >> 4) ^ ((l >> 1) & 3);
    int rdA = (l & 15) * 32 + slot * 8;                    // + fm*512
    int rdB = 4096 + (w * 64 + (l & 15)) * 32 + slot * 8;  // + fn*512

    f32x4 acc[8][4];
#pragma unroll
    for (int i = 0; i < 8; ++i)
#pragma unroll
        for (int q = 0; q < 4; ++q) acc[i][q] = (f32x4){0.f, 0.f, 0.f, 0.f};

    for (int kt = 0; kt < KDIM / 32; ++kt) {
        int k0 = kt * 32;
        __syncthreads();                   // prev round's reads done (WAR)
        gload16(pa0 + k0, &lds[w * 1024]);
        gload16(pa1 + k0, &lds[w * 1024 + 512]);
#pragma unroll
        for (int i = 0; i < 4; ++i)
            gload16(pb[i] + k0, &lds[4096 + w * 2048 + i * 512]);
        __syncthreads();                   // drains vmcnt: tile resident

        bf16x8 af[8], bf[4];
#pragma unroll
        for (int f = 0; f < 8; ++f) af[f] = *(const bf16x8*)&lds[rdA + f * 512];
#pragma unroll
        for (int f = 0; f < 4; ++f) bf[f] = *(const bf16x8*)&lds[rdB + f * 512];
#pragma unroll
        for (int fm = 0; fm < 8; ++fm)
#pragma unroll
            for (int fn = 0; fn < 4; ++fn)   // swapped: D[n][token]
                acc[fm][fn] = __builtin_amdgcn_mfma_f32_16x16x32_bf16(bf[fn], af[fm], acc[fm][fn], 0, 0, 0);
    }

    // epilogue: lane holds 4 consecutive n for token col l&15
    const float* be = bias + e * NDIM;
#pragma unroll
    for (int fm = 0; fm < 8; ++fm) {
        int r = m0 + fm * 16 + (l & 15);
        if (r >= cnt) continue;
        unsigned short* orow = Out + (size_t)(base + r) * NDIM;
#pragma unroll
        for (int fn = 0; fn < 4; ++fn) {
            int n = n0 + w * 64 + fn * 16 + (l >> 4) * 4;
            float4 bb4 = *(const float4*)&be[n];
            f32x4 a = acc[fm][fn];
            float v0 = a[0] + bb4.x, v1 = a[1] + bb4.y;
            float v2 = a[2] + bb4.z, v3 = a[3] + bb4.w;
            if (DOGELU) {
                v0 = gelu_fast(v0); v1 = gelu_fast(v1);
                v2 = gelu_fast(v2); v3 = gelu_fast(v3);
            }
            ushort4 pk = { f2bf(v0), f2bf(v1), f2bf(v2), f2bf(v3) };
            *(ushort4*)&orow[n] = pk;
        }
    }
}

// ---------------- combine (+ fused aux): out[t] = w1*y[row1] + (1-w1)*y[row2] ----------------
__global__ __launch_bounds__(256) void combine_kernel(
        const unsigned short* __restrict__ ybuf, const int* __restrict__ offs,
        const int* __restrict__ tk_pack, const float* __restrict__ tk_w,
        const int* __restrict__ tk_pos, const float* __restrict__ ssq,
        float* __restrict__ out) {
    if (blockIdx.x == BT / 2) {
        __shared__ float red[4];
        float s = 0.f;
        for (int i = threadIdx.x; i < BT; i += 256) s += ssq[i];
#pragma unroll
        for (int off = 32; off; off >>= 1) s += __shfl_xor(s, off, 64);
        if ((threadIdx.x & 63) == 0) red[threadIdx.x >> 6] = s;
        __syncthreads();
        if (threadIdx.x == 0)
            out[(size_t)BT * DD] = (red[0] + red[1] + red[2] + red[3]) * (float)EE / (float)BT;
        return;
    }
    int tid = threadIdx.x;
    int t  = blockIdx.x * 2 + (tid >> 7);
    int lt = tid & 127;
    int pk  = tk_pack[t];
    int pos = tk_pos[t];
    float w1 = tk_w[t], w2 = 1.f - w1;
    int r1 = offs[pk & 15] + (pos & 0xffff);
    int r2 = offs[pk >> 4] + (pos >> 16);
    ushort4 a0 = ((const ushort4*)(ybuf + (size_t)r1 * DD))[lt * 2];
    ushort4 a1 = ((const ushort4*)(ybuf + (size_t)r1 * DD))[lt * 2 + 1];
    ushort4 b0 = ((const ushort4*)(ybuf + (size_t)r2 * DD))[lt * 2];
    ushort4 b1 = ((const ushort4*)(ybuf + (size_t)r2 * DD))[lt * 2 + 1];
    float4 o0 = { w1 * bf2f(a0.x) + w2 * bf2f(b0.x), w1 * bf2f(a0.y) + w2 * bf2f(b0.y),
                  w1 * bf2f(a0.z) + w2 * bf2f(b0.z), w1 * bf2f(a0.w) + w2 * bf2f(b0.w) };
    float4 o1 = { w1 * bf2f(a1.x) + w2 * bf2f(b1.x), w1 * bf2f(a1.y) + w2 * bf2f(b1.y),
                  w1 * bf2f(a1.z) + w2 * bf2f(b1.z), w1 * bf2f(a1.w) + w2 * bf2f(b1.w) };
    float4* orow = (float4*)(out + (size_t)t * DD);
    orow[lt * 2]     = o0;
    orow[lt * 2 + 1] = o1;
}

extern "C" void kernel_launch(void* const* d_in, const int* in_sizes, int n_in,
                              void* d_out, int out_size, void* d_ws, size_t ws_size,
                              hipStream_t stream) {
    const float* x  = (const float*)d_in[0];
    const float* Wg = (const float*)d_in[1];
    const float* bg = (const float*)d_in[2];
    const float* W1 = (const float*)d_in[3];
    const float* b1 = (const float*)d_in[4];
    const float* W2 = (const float*)d_in[5];
    const float* b2 = (const float*)d_in[6];
    float* out = (float*)d_out;

    char* wsb = (char*)d_ws;
    int*   counts  = (int*)wsb;                         // 0 .. 32
    int*   sdone   = (int*)(wsb + 32);                  // 32 .. 36
    int*   offs    = (int*)(wsb + 64);                  // 64 .. 100
    int*   tok     = (int*)(wsb + 256);                 // -> 262400
    float* ssq     = (float*)(wsb + 262400);            // -> 295168
    int*   tk_pack = (int*)(wsb + 295168);              // -> 327936
    float* tk_w    = (float*)(wsb + 327936);            // -> 360704
    int*   tk_pos  = (int*)(wsb + 360704);              // -> 393472
    unsigned short* xbf  = (unsigned short*)(wsb + 393472);      // 16 MB -> 17170688
    unsigned short* W1T  = (unsigned short*)(wsb + 17170688);    // 32 MB -> 50725120
    unsigned short* W2T  = (unsigned short*)(wsb + 50725120);    // 32 MB -> 84279552
    unsigned short* hbuf = (unsigned short*)(wsb + 84279552);    // 64 MB -> 151388416
    // ybuf (33.5 MB bf16) overlays xbf+W1T — both dead once gemm1 has run
    unsigned short* ybuf = (unsigned short*)(wsb + 393472);

    hipMemsetAsync(wsb, 0, 64, stream);                 // counts + sdone

    prep_kernel<<<BT / 4 + 8192, 256, 0, stream>>>(x, Wg, bg, W1, W2,
                                                   tk_pack, tk_w, ssq, xbf, W1T, W2T);
    scatter_kernel<<<BT / 256, 256, 0, stream>>>(tk_pack, counts, sdone, tok, tk_pos, offs);
    moe_gemm_kernel<DD, HH, true, true><<<8 * (HH / 256) * (BT / 128), 256, 0, stream>>>(
        xbf, W1T, b1, counts, offs, tok, hbuf);
    moe_gemm_kernel<HH, DD, false, false><<<8 * (DD / 256) * (BT / 128), 256, 0, stream>>>(
        hbuf, W2T, b2, counts, offs, tok, ybuf);
    combine_kernel<<<BT / 2 + 1, 256, 0, stream>>>(ybuf, offs, tk_pack, tk_w, tk_pos, ssq, out);
}

// Round 13
// 293.542 us; speedup vs baseline: 1.4042x; 1.1055x over previous
//
#include <hip/hip_runtime.h>
#include <hip/hip_bf16.h>
#include <cmath>

#define BT 8192      // B*T tokens
#define DD 1024      // model dim
#define EE 8         // experts
#define HH 2048      // hidden

typedef __attribute__((ext_vector_type(8))) short bf16x8;
typedef __attribute__((ext_vector_type(4))) float f32x4;

__device__ __forceinline__ unsigned short f2bf(float f) {
    union { float f; unsigned u; } v; v.f = f;
    unsigned r = v.u + 0x7FFFu + ((v.u >> 16) & 1u);   // RNE
    return (unsigned short)(r >> 16);
}

__device__ __forceinline__ float bf2f(unsigned short s) {
    union { unsigned u; float f; } v; v.u = ((unsigned)s) << 16;
    return v.f;
}

// tanh-form GELU via sigmoid: max |diff vs exact erf-GELU| ~5e-4
__device__ __forceinline__ float gelu_fast(float x) {
    float z = x * (1.5957691216f + 0.071354816f * x * x);
    return x / (1.f + __expf(-z));
}

// async global->LDS, 16B per lane; LDS dest = wave-uniform base + lane*16
__device__ __forceinline__ void gload16(const void* g, void* l) {
    __builtin_amdgcn_global_load_lds(
        (const __attribute__((address_space(1))) void*)g,
        (__attribute__((address_space(3))) void*)l, 16, 0, 0);
}

// ---------------- prep: gating (+x->bf16) for bid<2048, W1 transpose otherwise ----------------
__global__ __launch_bounds__(256) void prep_kernel(
        const float* __restrict__ x, const float* __restrict__ Wg, const float* __restrict__ bg,
        const float* __restrict__ W1,
        int* __restrict__ tk_pack, float* __restrict__ tk_w, float* __restrict__ ssq,
        unsigned short* __restrict__ xbf, unsigned short* __restrict__ W1T) {
    __shared__ unsigned short tl[64][66];
    int bid = blockIdx.x;
    int tid = threadIdx.x;

    if (bid < BT / 4) {
        int lane = tid & 63;
        int wid  = tid >> 6;
        int t = bid * 4 + wid;
        const float* xr = x + (size_t)t * DD;
        unsigned* xbr = (unsigned*)(xbf + (size_t)t * DD);
        float acc[EE];
#pragma unroll
        for (int e = 0; e < EE; ++e) acc[e] = 0.f;
        for (int d = lane * 2; d < DD; d += 128) {
            float2 xv = *(const float2*)&xr[d];
            xbr[d >> 1] = (unsigned)f2bf(xv.x) | ((unsigned)f2bf(xv.y) << 16);
            const float* wr = Wg + d * EE;
#pragma unroll
            for (int e = 0; e < EE; ++e) acc[e] += xv.x * wr[e] + xv.y * wr[e + EE];
        }
#pragma unroll
        for (int off = 32; off; off >>= 1)
#pragma unroll
            for (int e = 0; e < EE; ++e) acc[e] += __shfl_xor(acc[e], off, 64);

        if (lane == 0) {
            float p[EE]; float m = -1e30f;
#pragma unroll
            for (int e = 0; e < EE; ++e) { p[e] = acc[e] + bg[e]; m = fmaxf(m, p[e]); }
            float s = 0.f;
#pragma unroll
            for (int e = 0; e < EE; ++e) { p[e] = expf(p[e] - m); s += p[e]; }
            float inv = 1.f / s, q = 0.f;
#pragma unroll
            for (int e = 0; e < EE; ++e) { p[e] = 0.99f * p[e] * inv + 0.00125f; q += p[e] * p[e]; }
            ssq[t] = q;
            int i1 = 0;
#pragma unroll
            for (int e = 1; e < EE; ++e) if (p[e] > p[i1]) i1 = e;    // lowest idx on tie
            int i2 = (i1 == 0) ? 1 : 0;
#pragma unroll
            for (int e = 0; e < EE; ++e) if (e != i1 && p[e] > p[i2]) i2 = e;
            tk_pack[t] = i1 | (i2 << 4);
            tk_w[t] = p[i1] / (p[i1] + p[i2]);         // w2 = 1 - w1
        }
        return;
    }

    // W1 [8][1024][2048] -> W1T [8][2048][1024]
    int bid2 = bid - BT / 4;
    int e = bid2 & 7; int t = bid2 >> 3;
    int c0 = (t & 31) * 64, r0 = (t >> 5) * 64;
    int ci = (tid & 31) * 2;
    int ri = tid >> 5;
    const float* src = W1 + ((size_t)e * DD + r0) * HH + c0;
#pragma unroll
    for (int j = 0; j < 8; ++j) {
        int r = ri + j * 8;
        float2 v = *(const float2*)&src[(size_t)r * HH + ci];
        tl[ci][r] = f2bf(v.x); tl[ci + 1][r] = f2bf(v.y);
    }
    __syncthreads();
    int r2 = (tid & 15) * 4, c2 = tid >> 4;
    unsigned short* dst = W1T + ((size_t)e * HH + c0) * DD + r0;
#pragma unroll
    for (int j = 0; j < 4; ++j) {
        int c = c2 + j * 16;
        ushort4 v = { tl[c][r2], tl[c][r2 + 1], tl[c][r2 + 2], tl[c][r2 + 3] };
        *(ushort4*)&dst[(size_t)c * DD + r2] = v;
    }
}

// ---------------- scatter + offsets (last-block): LDS histogram, 8 global atomics/block ----------------
__global__ __launch_bounds__(256) void scatter_kernel(const int* __restrict__ tk_pack,
                                                      int* __restrict__ counts,
                                                      int* __restrict__ done,
                                                      int* __restrict__ tok_list,
                                                      int* __restrict__ tk_pos,
                                                      int* __restrict__ offs) {
    __shared__ int lcnt[EE];
    __shared__ int gbase[EE];
    int tid = threadIdx.x;
    int t = blockIdx.x * 256 + tid;
    if (tid < EE) lcnt[tid] = 0;
    __syncthreads();
    int pk = tk_pack[t];
    int i1 = pk & 15, i2 = pk >> 4;
    int p1 = atomicAdd(&lcnt[i1], 1);
    int p2 = atomicAdd(&lcnt[i2], 1);
    __syncthreads();
    if (tid < EE) gbase[tid] = atomicAdd(&counts[tid], lcnt[tid]);
    __syncthreads();
    int q1 = gbase[i1] + p1, q2 = gbase[i2] + p2;
    tok_list[i1 * BT + q1] = t;
    tok_list[i2 * BT + q2] = t;
    tk_pos[t] = q1 | (q2 << 16);
    if (tid == 0) {
        __threadfence();
        if (atomicAdd(done, 1) == (int)gridDim.x - 1) {
            int a = 0;
#pragma unroll
            for (int e = 0; e < EE; ++e) { offs[e] = a; a += atomicAdd(&counts[e], 0); }
            offs[EE] = a;
        }
    }
}

// =====================================================================================
// grouped GEMM: 128x256 block, 4 waves each 128x64 (acc 8x4), BK=32,
// DOUBLE-buffered 48KB LDS (3 blocks/CU), counted vmcnt(6) (never drains in loop),
// 2 barriers/iter, stage-after-readers-done (R9's proven protocol).
// LDS per CU-K-step ~776 cyc vs MFMA 620 — near-balanced, latency hidden by dbuf+TLP.
// WTAIL: blocks >= ngemm do the W2 transpose (fills gemm1's scheduling bubbles).
// =====================================================================================
template<int KDIM, int NDIM, bool DOGELU, bool GATHER, bool WTAIL>
__global__ __launch_bounds__(256, 2) void moe_gemm_kernel(
        const unsigned short* __restrict__ Amat, const unsigned short* __restrict__ WT,
        const float* __restrict__ bias, const int* __restrict__ counts,
        const int* __restrict__ offs, const int* __restrict__ tok_list,
        unsigned short* __restrict__ Out,
        const float* __restrict__ W2, unsigned short* __restrict__ W2T, int ngemm) {
    // A: 2 bufs x 4096 shorts @0; B: 2 bufs x 8192 shorts @8192. 48 KB total.
    __shared__ __align__(16) unsigned short lds[24576];
    int bid = blockIdx.x;
    int tid = threadIdx.x;

    if (WTAIL && bid >= ngemm) {
        // W2 [8][2048][1024] -> W2T [8][1024][2048], runs in gemm1's tail/bubbles
        int b2 = bid - ngemm;
        int e = b2 & 7; int t = b2 >> 3;
        int c0 = (t & 15) * 64, r0 = (t >> 4) * 64;
        unsigned short (*tl)[66] = (unsigned short (*)[66])lds;
        int ci = (tid & 31) * 2, ri = tid >> 5;
        const float* src = W2 + ((size_t)e * HH + r0) * DD + c0;
#pragma unroll
        for (int j = 0; j < 8; ++j) {
            int r = ri + j * 8;
            float2 v = *(const float2*)&src[(size_t)r * DD + ci];
            tl[ci][r] = f2bf(v.x); tl[ci + 1][r] = f2bf(v.y);
        }
        __syncthreads();
        int r2 = (tid & 15) * 4, c2 = tid >> 4;
        unsigned short* dst = W2T + ((size_t)e * DD + c0) * HH + r0;
#pragma unroll
        for (int j = 0; j < 4; ++j) {
            int c = c2 + j * 16;
            ushort4 v = { tl[c][r2], tl[c][r2 + 1], tl[c][r2 + 2], tl[c][r2 + 3] };
            *(ushort4*)&dst[(size_t)c * HH + r2] = v;
        }
        return;
    }

    constexpr int NKT = KDIM / 32;
    constexpr int NNT = NDIM / 256;
    int e = bid & 7;                        // expert -> XCD pin
    int j = bid >> 3;
    int nt = j % NNT, mt = j / NNT;
    int cnt = counts[e];
    int m0 = mt * 128;
    if (m0 >= cnt) return;
    int n0 = nt * 256;
    int base = offs[e];

    int l = tid & 63, w = tid >> 6;

    // staging: src granule-swizzled, LDS linear (involution with read slot; 0 conflicts, R12)
    int g = (l & 3) ^ ((l >> 3) & 3);
    int ra0 = m0 + w * 32 + (l >> 2);      if (ra0 >= cnt) ra0 = cnt - 1;
    int ra1 = m0 + w * 32 + (l >> 2) + 16; if (ra1 >= cnt) ra1 = cnt - 1;
    size_t gr0 = GATHER ? (size_t)tok_list[e * BT + ra0] : (size_t)(base + ra0);
    size_t gr1 = GATHER ? (size_t)tok_list[e * BT + ra1] : (size_t)(base + ra1);
    const unsigned short* pa0 = Amat + gr0 * KDIM + g * 8;
    const unsigned short* pa1 = Amat + gr1 * KDIM + g * 8;
    const unsigned short* pb[4];
#pragma unroll
    for (int i = 0; i < 4; ++i)
        pb[i] = WT + ((size_t)e * NDIM + n0 + w * 64 + i * 16 + (l >> 2)) * KDIM + g * 8;

    int slot = (l >> 4) ^ ((l >> 1) & 3);
    int rdA = (l & 15) * 32 + slot * 8;                      // + cur*4096 + fm*512
    int rdB = (w * 64 + (l & 15)) * 32 + slot * 8;           // + 8192 + cur*8192 + fn*512

    f32x4 acc[8][4];
#pragma unroll
    for (int i = 0; i < 8; ++i)
#pragma unroll
        for (int q = 0; q < 4; ++q) acc[i][q] = (f32x4){0.f, 0.f, 0.f, 0.f};

#define STAGE(KOF, BUF)                                                           \
    gload16(pa0 + (KOF) * 32, &lds[(BUF) * 4096 + w * 1024]);                     \
    gload16(pa1 + (KOF) * 32, &lds[(BUF) * 4096 + w * 1024 + 512]);               \
    gload16(pb[0] + (KOF) * 32, &lds[8192 + (BUF) * 8192 + w * 2048]);            \
    gload16(pb[1] + (KOF) * 32, &lds[8192 + (BUF) * 8192 + w * 2048 + 512]);      \
    gload16(pb[2] + (KOF) * 32, &lds[8192 + (BUF) * 8192 + w * 2048 + 1024]);     \
    gload16(pb[3] + (KOF) * 32, &lds[8192 + (BUF) * 8192 + w * 2048 + 1536]);

    // prologue: tile0 -> buf0, tile1 -> buf1 (12 gload lines in flight)
    STAGE(0, 0)
    STAGE(1, 1)

    for (int kt = 0; kt < NKT; ++kt) {
        int cur = kt & 1;
        // counted wait: tile kt's 6 lines landed; tile kt+1's 6 stay in flight
        asm volatile("s_waitcnt vmcnt(6)" ::: "memory");
        __builtin_amdgcn_sched_barrier(0);
        __builtin_amdgcn_s_barrier();      // all waves confirmed their own loads
        __builtin_amdgcn_sched_barrier(0);

        int ab = cur * 4096 + rdA;
        int bb = 8192 + cur * 8192 + rdB;
        bf16x8 af[8], bf[4];
#pragma unroll
        for (int f = 0; f < 8; ++f) af[f] = *(const bf16x8*)&lds[ab + f * 512];
#pragma unroll
        for (int f = 0; f < 4; ++f) bf[f] = *(const bf16x8*)&lds[bb + f * 512];
#pragma unroll
        for (int fm = 0; fm < 8; ++fm)
#pragma unroll
            for (int fn = 0; fn < 4; ++fn)   // swapped: D[n][token]
                acc[fm][fn] = __builtin_amdgcn_mfma_f32_16x16x32_bf16(bf[fn], af[fm], acc[fm][fn], 0, 0, 0);

        // ds_reads consumed by MFMAs (lgkm deps) before this barrier; restage is WAR-safe
        __builtin_amdgcn_sched_barrier(0);
        __builtin_amdgcn_s_barrier();
        int kof = kt + 2; if (kof > NKT - 1) kof = NKT - 1;   // clamped tail keeps count uniform
        STAGE(kof, cur)
    }
#undef STAGE

    // epilogue: lane holds 4 consecutive n for token col l&15
    const float* be = bias + e * NDIM;
#pragma unroll
    for (int fm = 0; fm < 8; ++fm) {
        int r = m0 + fm * 16 + (l & 15);
        if (r >= cnt) continue;
        unsigned short* orow = Out + (size_t)(base + r) * NDIM;
#pragma unroll
        for (int fn = 0; fn < 4; ++fn) {
            int n = n0 + w * 64 + fn * 16 + (l >> 4) * 4;
            float4 bb4 = *(const float4*)&be[n];
            f32x4 a = acc[fm][fn];
            float v0 = a[0] + bb4.x, v1 = a[1] + bb4.y;
            float v2 = a[2] + bb4.z, v3 = a[3] + bb4.w;
            if (DOGELU) {
                v0 = gelu_fast(v0); v1 = gelu_fast(v1);
                v2 = gelu_fast(v2); v3 = gelu_fast(v3);
            }
            ushort4 pk = { f2bf(v0), f2bf(v1), f2bf(v2), f2bf(v3) };
            *(ushort4*)&orow[n] = pk;
        }
    }
}

// ---------------- combine (+ fused aux): out[t] = w1*y[row1] + (1-w1)*y[row2] ----------------
__global__ __launch_bounds__(256) void combine_kernel(
        const unsigned short* __restrict__ ybuf, const int* __restrict__ offs,
        const int* __restrict__ tk_pack, const float* __restrict__ tk_w,
        const int* __restrict__ tk_pos, const float* __restrict__ ssq,
        float* __restrict__ out) {
    if (blockIdx.x == BT / 2) {
        __shared__ float red[4];
        float s = 0.f;
        for (int i = threadIdx.x; i < BT; i += 256) s += ssq[i];
#pragma unroll
        for (int off = 32; off; off >>= 1) s += __shfl_xor(s, off, 64);
        if ((threadIdx.x & 63) == 0) red[threadIdx.x >> 6] = s;
        __syncthreads();
        if (threadIdx.x == 0)
            out[(size_t)BT * DD] = (red[0] + red[1] + red[2] + red[3]) * (float)EE / (float)BT;
        return;
    }
    int tid = threadIdx.x;
    int t  = blockIdx.x * 2 + (tid >> 7);
    int lt = tid & 127;
    int pk  = tk_pack[t];
    int pos = tk_pos[t];
    float w1 = tk_w[t], w2 = 1.f - w1;
    int r1 = offs[pk & 15] + (pos & 0xffff);
    int r2 = offs[pk >> 4] + (pos >> 16);
    ushort4 a0 = ((const ushort4*)(ybuf + (size_t)r1 * DD))[lt * 2];
    ushort4 a1 = ((const ushort4*)(ybuf + (size_t)r1 * DD))[lt * 2 + 1];
    ushort4 b0 = ((const ushort4*)(ybuf + (size_t)r2 * DD))[lt * 2];
    ushort4 b1 = ((const ushort4*)(ybuf + (size_t)r2 * DD))[lt * 2 + 1];
    float4 o0 = { w1 * bf2f(a0.x) + w2 * bf2f(b0.x), w1 * bf2f(a0.y) + w2 * bf2f(b0.y),
                  w1 * bf2f(a0.z) + w2 * bf2f(b0.z), w1 * bf2f(a0.w) + w2 * bf2f(b0.w) };
    float4 o1 = { w1 * bf2f(a1.x) + w2 * bf2f(b1.x), w1 * bf2f(a1.y) + w2 * bf2f(b1.y),
                  w1 * bf2f(a1.z) + w2 * bf2f(b1.z), w1 * bf2f(a1.w) + w2 * bf2f(b1.w) };
    float4* orow = (float4*)(out + (size_t)t * DD);
    orow[lt * 2]     = o0;
    orow[lt * 2 + 1] = o1;
}

extern "C" void kernel_launch(void* const* d_in, const int* in_sizes, int n_in,
                              void* d_out, int out_size, void* d_ws, size_t ws_size,
                              hipStream_t stream) {
    const float* x  = (const float*)d_in[0];
    const float* Wg = (const float*)d_in[1];
    const float* bg = (const float*)d_in[2];
    const float* W1 = (const float*)d_in[3];
    const float* b1 = (const float*)d_in[4];
    const float* W2 = (const float*)d_in[5];
    const float* b2 = (const float*)d_in[6];
    float* out = (float*)d_out;

    char* wsb = (char*)d_ws;
    int*   counts  = (int*)wsb;                         // 0 .. 32
    int*   sdone   = (int*)(wsb + 32);                  // 32 .. 36
    int*   offs    = (int*)(wsb + 64);                  // 64 .. 100
    int*   tok     = (int*)(wsb + 256);                 // -> 262400
    float* ssq     = (float*)(wsb + 262400);            // -> 295168
    int*   tk_pack = (int*)(wsb + 295168);              // -> 327936
    float* tk_w    = (float*)(wsb + 327936);            // -> 360704
    int*   tk_pos  = (int*)(wsb + 360704);              // -> 393472
    unsigned short* xbf  = (unsigned short*)(wsb + 393472);      // 16 MB -> 17170688
    unsigned short* W1T  = (unsigned short*)(wsb + 17170688);    // 32 MB -> 50725120
    unsigned short* W2T  = (unsigned short*)(wsb + 50725120);    // 32 MB -> 84279552
    unsigned short* hbuf = (unsigned short*)(wsb + 84279552);    // 64 MB -> 151388416
    // ybuf (33.5 MB bf16) overlays xbf+W1T — both dead once gemm1 has run
    unsigned short* ybuf = (unsigned short*)(wsb + 393472);

    hipMemsetAsync(wsb, 0, 64, stream);                 // counts + sdone

    prep_kernel<<<BT / 4 + 4096, 256, 0, stream>>>(x, Wg, bg, W1,
                                                   tk_pack, tk_w, ssq, xbf, W1T);
    scatter_kernel<<<BT / 256, 256, 0, stream>>>(tk_pack, counts, sdone, tok, tk_pos, offs);
    // gemm1 (4096 gemm blocks) + W2-transpose tail (4096 blocks in gemm1's bubbles)
    moe_gemm_kernel<DD, HH, true, true, true><<<8192, 256, 0, stream>>>(
        xbf, W1T, b1, counts, offs, tok, hbuf, W2, W2T, 4096);
    moe_gemm_kernel<HH, DD, false, false, false><<<2048, 256, 0, stream>>>(
        hbuf, W2T, b2, counts, offs, tok, ybuf, nullptr, nullptr, 2048);
    combine_kernel<<<BT / 2 + 1, 256, 0, stream>>>(ybuf, offs, tk_pack, tk_w, tk_pos, ssq, out);
}

// Round 14
// 277.698 us; speedup vs baseline: 1.4843x; 1.0571x over previous
//
#include <hip/hip_runtime.h>
#include <hip/hip_bf16.h>
#include <cmath>

#define BT 8192      // B*T tokens
#define DD 1024      // model dim
#define EE 8         // experts
#define HH 2048      // hidden

typedef __attribute__((ext_vector_type(8))) short bf16x8;
typedef __attribute__((ext_vector_type(4))) float f32x4;

__device__ __forceinline__ unsigned short f2bf(float f) {
    union { float f; unsigned u; } v; v.f = f;
    unsigned r = v.u + 0x7FFFu + ((v.u >> 16) & 1u);   // RNE
    return (unsigned short)(r >> 16);
}

__device__ __forceinline__ float bf2f(unsigned short s) {
    union { unsigned u; float f; } v; v.u = ((unsigned)s) << 16;
    return v.f;
}

// tanh-form GELU via sigmoid: max |diff vs exact erf-GELU| ~5e-4
__device__ __forceinline__ float gelu_fast(float x) {
    float z = x * (1.5957691216f + 0.071354816f * x * x);
    return x / (1.f + __expf(-z));
}

// async global->LDS, 16B per lane; LDS dest = wave-uniform base + lane*16
__device__ __forceinline__ void gload16(const void* g, void* l) {
    __builtin_amdgcn_global_load_lds(
        (const __attribute__((address_space(1))) void*)g,
        (__attribute__((address_space(3))) void*)l, 16, 0, 0);
}

// ---------------- prep: gating (+x->bf16) for bid<2048, W1 transpose otherwise ----------------
__global__ __launch_bounds__(256) void prep_kernel(
        const float* __restrict__ x, const float* __restrict__ Wg, const float* __restrict__ bg,
        const float* __restrict__ W1,
        int* __restrict__ tk_pack, float* __restrict__ tk_w, float* __restrict__ ssq,
        unsigned short* __restrict__ xbf, unsigned short* __restrict__ W1T) {
    __shared__ unsigned short tl[64][66];
    int bid = blockIdx.x;
    int tid = threadIdx.x;

    if (bid < BT / 4) {
        int lane = tid & 63;
        int wid  = tid >> 6;
        int t = bid * 4 + wid;
        const float* xr = x + (size_t)t * DD;
        unsigned* xbr = (unsigned*)(xbf + (size_t)t * DD);
        float acc[EE];
#pragma unroll
        for (int e = 0; e < EE; ++e) acc[e] = 0.f;
        for (int d = lane * 2; d < DD; d += 128) {
            float2 xv = *(const float2*)&xr[d];
            xbr[d >> 1] = (unsigned)f2bf(xv.x) | ((unsigned)f2bf(xv.y) << 16);
            const float* wr = Wg + d * EE;
#pragma unroll
            for (int e = 0; e < EE; ++e) acc[e] += xv.x * wr[e] + xv.y * wr[e + EE];
        }
#pragma unroll
        for (int off = 32; off; off >>= 1)
#pragma unroll
            for (int e = 0; e < EE; ++e) acc[e] += __shfl_xor(acc[e], off, 64);

        if (lane == 0) {
            float p[EE]; float m = -1e30f;
#pragma unroll
            for (int e = 0; e < EE; ++e) { p[e] = acc[e] + bg[e]; m = fmaxf(m, p[e]); }
            float s = 0.f;
#pragma unroll
            for (int e = 0; e < EE; ++e) { p[e] = expf(p[e] - m); s += p[e]; }
            float inv = 1.f / s, q = 0.f;
#pragma unroll
            for (int e = 0; e < EE; ++e) { p[e] = 0.99f * p[e] * inv + 0.00125f; q += p[e] * p[e]; }
            ssq[t] = q;
            int i1 = 0;
#pragma unroll
            for (int e = 1; e < EE; ++e) if (p[e] > p[i1]) i1 = e;    // lowest idx on tie
            int i2 = (i1 == 0) ? 1 : 0;
#pragma unroll
            for (int e = 0; e < EE; ++e) if (e != i1 && p[e] > p[i2]) i2 = e;
            tk_pack[t] = i1 | (i2 << 4);
            tk_w[t] = p[i1] / (p[i1] + p[i2]);         // w2 = 1 - w1
        }
        return;
    }

    // W1 [8][1024][2048] -> W1T [8][2048][1024]
    int bid2 = bid - BT / 4;
    int e = bid2 & 7; int t = bid2 >> 3;
    int c0 = (t & 31) * 64, r0 = (t >> 5) * 64;
    int ci = (tid & 31) * 2;
    int ri = tid >> 5;
    const float* src = W1 + ((size_t)e * DD + r0) * HH + c0;
#pragma unroll
    for (int j = 0; j < 8; ++j) {
        int r = ri + j * 8;
        float2 v = *(const float2*)&src[(size_t)r * HH + ci];
        tl[ci][r] = f2bf(v.x); tl[ci + 1][r] = f2bf(v.y);
    }
    __syncthreads();
    int r2 = (tid & 15) * 4, c2 = tid >> 4;
    unsigned short* dst = W1T + ((size_t)e * HH + c0) * DD + r0;
#pragma unroll
    for (int j = 0; j < 4; ++j) {
        int c = c2 + j * 16;
        ushort4 v = { tl[c][r2], tl[c][r2 + 1], tl[c][r2 + 2], tl[c][r2 + 3] };
        *(ushort4*)&dst[(size_t)c * DD + r2] = v;
    }
}

// ---------------- scatter + offsets (last-block): LDS histogram, 8 global atomics/block ----------------
__global__ __launch_bounds__(256) void scatter_kernel(const int* __restrict__ tk_pack,
                                                      int* __restrict__ counts,
                                                      int* __restrict__ done,
                                                      int* __restrict__ tok_list,
                                                      int* __restrict__ tk_pos,
                                                      int* __restrict__ offs) {
    __shared__ int lcnt[EE];
    __shared__ int gbase[EE];
    int tid = threadIdx.x;
    int t = blockIdx.x * 256 + tid;
    if (tid < EE) lcnt[tid] = 0;
    __syncthreads();
    int pk = tk_pack[t];
    int i1 = pk & 15, i2 = pk >> 4;
    int p1 = atomicAdd(&lcnt[i1], 1);
    int p2 = atomicAdd(&lcnt[i2], 1);
    __syncthreads();
    if (tid < EE) gbase[tid] = atomicAdd(&counts[tid], lcnt[tid]);
    __syncthreads();
    int q1 = gbase[i1] + p1, q2 = gbase[i2] + p2;
    tok_list[i1 * BT + q1] = t;
    tok_list[i2 * BT + q2] = t;
    tk_pos[t] = q1 | (q2 << 16);
    if (tid == 0) {
        __threadfence();
        if (atomicAdd(done, 1) == (int)gridDim.x - 1) {
            int a = 0;
#pragma unroll
            for (int e = 0; e < EE; ++e) { offs[e] = a; a += atomicAdd(&counts[e], 0); }
            offs[EE] = a;
        }
    }
}

// =====================================================================================
// grouped GEMM: 128x256 block, 4 waves each 128x64 (acc 8x4), BK=32,
// DOUBLE-buffered 48KB LDS, counted vmcnt(6), 2 barriers/iter, stage-after-readers-done.
// R14 change: __launch_bounds__(256,3) -> 3 blocks/CU (12 waves, 3 waves/SIMD) — TLP
// to cover the latency that 1.6 waves/SIMD (R13, launch_bounds(256,2)) left exposed.
// WTAIL: blocks >= ngemm do the W2 transpose (fills gemm1's scheduling bubbles).
// =====================================================================================
template<int KDIM, int NDIM, bool DOGELU, bool GATHER, bool WTAIL>
__global__ __launch_bounds__(256, 3) void moe_gemm_kernel(
        const unsigned short* __restrict__ Amat, const unsigned short* __restrict__ WT,
        const float* __restrict__ bias, const int* __restrict__ counts,
        const int* __restrict__ offs, const int* __restrict__ tok_list,
        unsigned short* __restrict__ Out,
        const float* __restrict__ W2, unsigned short* __restrict__ W2T, int ngemm) {
    // A: 2 bufs x 4096 shorts @0; B: 2 bufs x 8192 shorts @8192. 48 KB total.
    __shared__ __align__(16) unsigned short lds[24576];
    int bid = blockIdx.x;
    int tid = threadIdx.x;

    if (WTAIL && bid >= ngemm) {
        // W2 [8][2048][1024] -> W2T [8][1024][2048], runs in gemm1's tail/bubbles
        int b2 = bid - ngemm;
        int e = b2 & 7; int t = b2 >> 3;
        int c0 = (t & 15) * 64, r0 = (t >> 4) * 64;
        unsigned short (*tl)[66] = (unsigned short (*)[66])lds;
        int ci = (tid & 31) * 2, ri = tid >> 5;
        const float* src = W2 + ((size_t)e * HH + r0) * DD + c0;
#pragma unroll
        for (int j = 0; j < 8; ++j) {
            int r = ri + j * 8;
            float2 v = *(const float2*)&src[(size_t)r * DD + ci];
            tl[ci][r] = f2bf(v.x); tl[ci + 1][r] = f2bf(v.y);
        }
        __syncthreads();
        int r2 = (tid & 15) * 4, c2 = tid >> 4;
        unsigned short* dst = W2T + ((size_t)e * DD + c0) * HH + r0;
#pragma unroll
        for (int j = 0; j < 4; ++j) {
            int c = c2 + j * 16;
            ushort4 v = { tl[c][r2], tl[c][r2 + 1], tl[c][r2 + 2], tl[c][r2 + 3] };
            *(ushort4*)&dst[(size_t)c * HH + r2] = v;
        }
        return;
    }

    constexpr int NKT = KDIM / 32;
    constexpr int NNT = NDIM / 256;
    int e = bid & 7;                        // expert -> XCD pin
    int j = bid >> 3;
    int nt = j % NNT, mt = j / NNT;
    int cnt = counts[e];
    int m0 = mt * 128;
    if (m0 >= cnt) return;
    int n0 = nt * 256;
    int base = offs[e];

    int l = tid & 63, w = tid >> 6;

    // staging: src granule-swizzled, LDS linear (involution with read slot)
    int g = (l & 3) ^ ((l >> 3) & 3);
    int ra0 = m0 + w * 32 + (l >> 2);      if (ra0 >= cnt) ra0 = cnt - 1;
    int ra1 = m0 + w * 32 + (l >> 2) + 16; if (ra1 >= cnt) ra1 = cnt - 1;
    size_t gr0 = GATHER ? (size_t)tok_list[e * BT + ra0] : (size_t)(base + ra0);
    size_t gr1 = GATHER ? (size_t)tok_list[e * BT + ra1] : (size_t)(base + ra1);
    const unsigned short* pa0 = Amat + gr0 * KDIM + g * 8;
    const unsigned short* pa1 = Amat + gr1 * KDIM + g * 8;
    const unsigned short* pb[4];
#pragma unroll
    for (int i = 0; i < 4; ++i)
        pb[i] = WT + ((size_t)e * NDIM + n0 + w * 64 + i * 16 + (l >> 2)) * KDIM + g * 8;

    int slot = (l >> 4) ^ ((l >> 1) & 3);
    int rdA = (l & 15) * 32 + slot * 8;                      // + cur*4096 + fm*512
    int rdB = (w * 64 + (l & 15)) * 32 + slot * 8;           // + 8192 + cur*8192 + fn*512

    f32x4 acc[8][4];
#pragma unroll
    for (int i = 0; i < 8; ++i)
#pragma unroll
        for (int q = 0; q < 4; ++q) acc[i][q] = (f32x4){0.f, 0.f, 0.f, 0.f};

#define STAGE(KOF, BUF)                                                           \
    gload16(pa0 + (KOF) * 32, &lds[(BUF) * 4096 + w * 1024]);                     \
    gload16(pa1 + (KOF) * 32, &lds[(BUF) * 4096 + w * 1024 + 512]);               \
    gload16(pb[0] + (KOF) * 32, &lds[8192 + (BUF) * 8192 + w * 2048]);            \
    gload16(pb[1] + (KOF) * 32, &lds[8192 + (BUF) * 8192 + w * 2048 + 512]);      \
    gload16(pb[2] + (KOF) * 32, &lds[8192 + (BUF) * 8192 + w * 2048 + 1024]);     \
    gload16(pb[3] + (KOF) * 32, &lds[8192 + (BUF) * 8192 + w * 2048 + 1536]);

    // prologue: tile0 -> buf0, tile1 -> buf1 (12 gload lines in flight)
    STAGE(0, 0)
    STAGE(1, 1)

    for (int kt = 0; kt < NKT; ++kt) {
        int cur = kt & 1;
        // counted wait: tile kt's 6 lines landed; tile kt+1's 6 stay in flight
        asm volatile("s_waitcnt vmcnt(6)" ::: "memory");
        __builtin_amdgcn_sched_barrier(0);
        __builtin_amdgcn_s_barrier();      // all waves confirmed their own loads
        __builtin_amdgcn_sched_barrier(0);

        int ab = cur * 4096 + rdA;
        int bb = 8192 + cur * 8192 + rdB;
        bf16x8 af[8], bf[4];
#pragma unroll
        for (int f = 0; f < 8; ++f) af[f] = *(const bf16x8*)&lds[ab + f * 512];
#pragma unroll
        for (int f = 0; f < 4; ++f) bf[f] = *(const bf16x8*)&lds[bb + f * 512];
#pragma unroll
        for (int fm = 0; fm < 8; ++fm)
#pragma unroll
            for (int fn = 0; fn < 4; ++fn)   // swapped: D[n][token]
                acc[fm][fn] = __builtin_amdgcn_mfma_f32_16x16x32_bf16(bf[fn], af[fm], acc[fm][fn], 0, 0, 0);

        // ds_reads consumed by MFMAs (lgkm deps) before this barrier; restage is WAR-safe
        __builtin_amdgcn_sched_barrier(0);
        __builtin_amdgcn_s_barrier();
        int kof = kt + 2; if (kof > NKT - 1) kof = NKT - 1;   // clamped tail keeps count uniform
        STAGE(kof, cur)
    }
#undef STAGE

    // epilogue: lane holds 4 consecutive n for token col l&15
    const float* be = bias + e * NDIM;
#pragma unroll
    for (int fm = 0; fm < 8; ++fm) {
        int r = m0 + fm * 16 + (l & 15);
        if (r >= cnt) continue;
        unsigned short* orow = Out + (size_t)(base + r) * NDIM;
#pragma unroll
        for (int fn = 0; fn < 4; ++fn) {
            int n = n0 + w * 64 + fn * 16 + (l >> 4) * 4;
            float4 bb4 = *(const float4*)&be[n];
            f32x4 a = acc[fm][fn];
            float v0 = a[0] + bb4.x, v1 = a[1] + bb4.y;
            float v2 = a[2] + bb4.z, v3 = a[3] + bb4.w;
            if (DOGELU) {
                v0 = gelu_fast(v0); v1 = gelu_fast(v1);
                v2 = gelu_fast(v2); v3 = gelu_fast(v3);
            }
            ushort4 pk = { f2bf(v0), f2bf(v1), f2bf(v2), f2bf(v3) };
            *(ushort4*)&orow[n] = pk;
        }
    }
}

// ---------------- combine (+ fused aux): out[t] = w1*y[row1] + (1-w1)*y[row2] ----------------
__global__ __launch_bounds__(256) void combine_kernel(
        const unsigned short* __restrict__ ybuf, const int* __restrict__ offs,
        const int* __restrict__ tk_pack, const float* __restrict__ tk_w,
        const int* __restrict__ tk_pos, const float* __restrict__ ssq,
        float* __restrict__ out) {
    if (blockIdx.x == BT / 2) {
        __shared__ float red[4];
        float s = 0.f;
        for (int i = threadIdx.x; i < BT; i += 256) s += ssq[i];
#pragma unroll
        for (int off = 32; off; off >>= 1) s += __shfl_xor(s, off, 64);
        if ((threadIdx.x & 63) == 0) red[threadIdx.x >> 6] = s;
        __syncthreads();
        if (threadIdx.x == 0)
            out[(size_t)BT * DD] = (red[0] + red[1] + red[2] + red[3]) * (float)EE / (float)BT;
        return;
    }
    int tid = threadIdx.x;
    int t  = blockIdx.x * 2 + (tid >> 7);
    int lt = tid & 127;
    int pk  = tk_pack[t];
    int pos = tk_pos[t];
    float w1 = tk_w[t], w2 = 1.f - w1;
    int r1 = offs[pk & 15] + (pos & 0xffff);
    int r2 = offs[pk >> 4] + (pos >> 16);
    ushort4 a0 = ((const ushort4*)(ybuf + (size_t)r1 * DD))[lt * 2];
    ushort4 a1 = ((const ushort4*)(ybuf + (size_t)r1 * DD))[lt * 2 + 1];
    ushort4 b0 = ((const ushort4*)(ybuf + (size_t)r2 * DD))[lt * 2];
    ushort4 b1 = ((const ushort4*)(ybuf + (size_t)r2 * DD))[lt * 2 + 1];
    float4 o0 = { w1 * bf2f(a0.x) + w2 * bf2f(b0.x), w1 * bf2f(a0.y) + w2 * bf2f(b0.y),
                  w1 * bf2f(a0.z) + w2 * bf2f(b0.z), w1 * bf2f(a0.w) + w2 * bf2f(b0.w) };
    float4 o1 = { w1 * bf2f(a1.x) + w2 * bf2f(b1.x), w1 * bf2f(a1.y) + w2 * bf2f(b1.y),
                  w1 * bf2f(a1.z) + w2 * bf2f(b1.z), w1 * bf2f(a1.w) + w2 * bf2f(b1.w) };
    float4* orow = (float4*)(out + (size_t)t * DD);
    orow[lt * 2]     = o0;
    orow[lt * 2 + 1] = o1;
}

extern "C" void kernel_launch(void* const* d_in, const int* in_sizes, int n_in,
                              void* d_out, int out_size, void* d_ws, size_t ws_size,
                              hipStream_t stream) {
    const float* x  = (const float*)d_in[0];
    const float* Wg = (const float*)d_in[1];
    const float* bg = (const float*)d_in[2];
    const float* W1 = (const float*)d_in[3];
    const float* b1 = (const float*)d_in[4];
    const float* W2 = (const float*)d_in[5];
    const float* b2 = (const float*)d_in[6];
    float* out = (float*)d_out;

    char* wsb = (char*)d_ws;
    int*   counts  = (int*)wsb;                         // 0 .. 32
    int*   sdone   = (int*)(wsb + 32);                  // 32 .. 36
    int*   offs    = (int*)(wsb + 64);                  // 64 .. 100
    int*   tok     = (int*)(wsb + 256);                 // -> 262400
    float* ssq     = (float*)(wsb + 262400);            // -> 295168
    int*   tk_pack = (int*)(wsb + 295168);              // -> 327936
    float* tk_w    = (float*)(wsb + 327936);            // -> 360704
    int*   tk_pos  = (int*)(wsb + 360704);              // -> 393472
    unsigned short* xbf  = (unsigned short*)(wsb + 393472);      // 16 MB -> 17170688
    unsigned short* W1T  = (unsigned short*)(wsb + 17170688);    // 32 MB -> 50725120
    unsigned short* W2T  = (unsigned short*)(wsb + 50725120);    // 32 MB -> 84279552
    unsigned short* hbuf = (unsigned short*)(wsb + 84279552);    // 64 MB -> 151388416
    // ybuf (33.5 MB bf16) overlays xbf+W1T — both dead once gemm1 has run
    unsigned short* ybuf = (unsigned short*)(wsb + 393472);

    hipMemsetAsync(wsb, 0, 64, stream);                 // counts + sdone

    prep_kernel<<<BT / 4 + 4096, 256, 0, stream>>>(x, Wg, bg, W1,
                                                   tk_pack, tk_w, ssq, xbf, W1T);
    scatter_kernel<<<BT / 256, 256, 0, stream>>>(tk_pack, counts, sdone, tok, tk_pos, offs);
    // gemm1 (4096 gemm blocks) + W2-transpose tail (4096 blocks in gemm1's bubbles)
    moe_gemm_kernel<DD, HH, true, true, true><<<8192, 256, 0, stream>>>(
        xbf, W1T, b1, counts, offs, tok, hbuf, W2, W2T, 4096);
    moe_gemm_kernel<HH, DD, false, false, false><<<2048, 256, 0, stream>>>(
        hbuf, W2T, b2, counts, offs, tok, ybuf, nullptr, nullptr, 2048);
    combine_kernel<<<BT / 2 + 1, 256, 0, stream>>>(ybuf, offs, tk_pack, tk_w, tk_pos, ssq, out);
}

// Round 15
// 273.504 us; speedup vs baseline: 1.5071x; 1.0153x over previous
//
#include <hip/hip_runtime.h>
#include <hip/hip_bf16.h>
#include <cmath>

#define BT 8192      // B*T tokens
#define DD 1024      // model dim
#define EE 8         // experts
#define HH 2048      // hidden

typedef __attribute__((ext_vector_type(8))) short bf16x8;
typedef __attribute__((ext_vector_type(4))) float f32x4;

__device__ __forceinline__ unsigned short f2bf(float f) {
    union { float f; unsigned u; } v; v.f = f;
    unsigned r = v.u + 0x7FFFu + ((v.u >> 16) & 1u);   // RNE
    return (unsigned short)(r >> 16);
}

__device__ __forceinline__ float bf2f(unsigned short s) {
    union { unsigned u; float f; } v; v.u = ((unsigned)s) << 16;
    return v.f;
}

// tanh-form GELU via sigmoid: max |diff vs exact erf-GELU| ~5e-4
__device__ __forceinline__ float gelu_fast(float x) {
    float z = x * (1.5957691216f + 0.071354816f * x * x);
    return x / (1.f + __expf(-z));
}

// async global->LDS, 16B per lane; LDS dest = wave-uniform base + lane*16
__device__ __forceinline__ void gload16(const void* g, void* l) {
    __builtin_amdgcn_global_load_lds(
        (const __attribute__((address_space(1))) void*)g,
        (__attribute__((address_space(3))) void*)l, 16, 0, 0);
}

// ---------------- prep: gating (+x->bf16) for bid<2048, W1 transpose otherwise ----------------
__global__ __launch_bounds__(256) void prep_kernel(
        const float* __restrict__ x, const float* __restrict__ Wg, const float* __restrict__ bg,
        const float* __restrict__ W1,
        int* __restrict__ tk_pack, float* __restrict__ tk_w, float* __restrict__ ssq,
        unsigned short* __restrict__ xbf, unsigned short* __restrict__ W1T) {
    __shared__ unsigned short tl[64][66];
    int bid = blockIdx.x;
    int tid = threadIdx.x;

    if (bid < BT / 4) {
        int lane = tid & 63;
        int wid  = tid >> 6;
        int t = bid * 4 + wid;
        const float* xr = x + (size_t)t * DD;
        unsigned* xbr = (unsigned*)(xbf + (size_t)t * DD);
        float acc[EE];
#pragma unroll
        for (int e = 0; e < EE; ++e) acc[e] = 0.f;
        for (int d = lane * 2; d < DD; d += 128) {
            float2 xv = *(const float2*)&xr[d];
            xbr[d >> 1] = (unsigned)f2bf(xv.x) | ((unsigned)f2bf(xv.y) << 16);
            const float* wr = Wg + d * EE;
#pragma unroll
            for (int e = 0; e < EE; ++e) acc[e] += xv.x * wr[e] + xv.y * wr[e + EE];
        }
#pragma unroll
        for (int off = 32; off; off >>= 1)
#pragma unroll
            for (int e = 0; e < EE; ++e) acc[e] += __shfl_xor(acc[e], off, 64);

        if (lane == 0) {
            float p[EE]; float m = -1e30f;
#pragma unroll
            for (int e = 0; e < EE; ++e) { p[e] = acc[e] + bg[e]; m = fmaxf(m, p[e]); }
            float s = 0.f;
#pragma unroll
            for (int e = 0; e < EE; ++e) { p[e] = expf(p[e] - m); s += p[e]; }
            float inv = 1.f / s, q = 0.f;
#pragma unroll
            for (int e = 0; e < EE; ++e) { p[e] = 0.99f * p[e] * inv + 0.00125f; q += p[e] * p[e]; }
            ssq[t] = q;
            int i1 = 0;
#pragma unroll
            for (int e = 1; e < EE; ++e) if (p[e] > p[i1]) i1 = e;    // lowest idx on tie
            int i2 = (i1 == 0) ? 1 : 0;
#pragma unroll
            for (int e = 0; e < EE; ++e) if (e != i1 && p[e] > p[i2]) i2 = e;
            tk_pack[t] = i1 | (i2 << 4);
            tk_w[t] = p[i1] / (p[i1] + p[i2]);         // w2 = 1 - w1
        }
        return;
    }

    // W1 [8][1024][2048] -> W1T [8][2048][1024]
    int bid2 = bid - BT / 4;
    int e = bid2 & 7; int t = bid2 >> 3;
    int c0 = (t & 31) * 64, r0 = (t >> 5) * 64;
    int ci = (tid & 31) * 2;
    int ri = tid >> 5;
    const float* src = W1 + ((size_t)e * DD + r0) * HH + c0;
#pragma unroll
    for (int j = 0; j < 8; ++j) {
        int r = ri + j * 8;
        float2 v = *(const float2*)&src[(size_t)r * HH + ci];
        tl[ci][r] = f2bf(v.x); tl[ci + 1][r] = f2bf(v.y);
    }
    __syncthreads();
    int r2 = (tid & 15) * 4, c2 = tid >> 4;
    unsigned short* dst = W1T + ((size_t)e * HH + c0) * DD + r0;
#pragma unroll
    for (int j = 0; j < 4; ++j) {
        int c = c2 + j * 16;
        ushort4 v = { tl[c][r2], tl[c][r2 + 1], tl[c][r2 + 2], tl[c][r2 + 3] };
        *(ushort4*)&dst[(size_t)c * DD + r2] = v;
    }
}

// ---------------- scatter + offsets (last-block): LDS histogram, 8 global atomics/block ----------------
__global__ __launch_bounds__(256) void scatter_kernel(const int* __restrict__ tk_pack,
                                                      int* __restrict__ counts,
                                                      int* __restrict__ done,
                                                      int* __restrict__ tok_list,
                                                      int* __restrict__ tk_pos,
                                                      int* __restrict__ offs) {
    __shared__ int lcnt[EE];
    __shared__ int gbase[EE];
    int tid = threadIdx.x;
    int t = blockIdx.x * 256 + tid;
    if (tid < EE) lcnt[tid] = 0;
    __syncthreads();
    int pk = tk_pack[t];
    int i1 = pk & 15, i2 = pk >> 4;
    int p1 = atomicAdd(&lcnt[i1], 1);
    int p2 = atomicAdd(&lcnt[i2], 1);
    __syncthreads();
    if (tid < EE) gbase[tid] = atomicAdd(&counts[tid], lcnt[tid]);
    __syncthreads();
    int q1 = gbase[i1] + p1, q2 = gbase[i2] + p2;
    tok_list[i1 * BT + q1] = t;
    tok_list[i2 * BT + q2] = t;
    tk_pos[t] = q1 | (q2 << 16);
    if (tid == 0) {
        __threadfence();
        if (atomicAdd(done, 1) == (int)gridDim.x - 1) {
            int a = 0;
#pragma unroll
            for (int e = 0; e < EE; ++e) { offs[e] = a; a += atomicAdd(&counts[e], 0); }
            offs[EE] = a;
        }
    }
}

// =====================================================================================
// grouped GEMM: 128x256 block, 4 waves each 128x64 (acc 8x4), BK=32, dbuf 48KB LDS,
// 3 blocks/CU. R15: guide-verified MINIMAL 2-PHASE loop — STAGE(next) issued FIRST,
// then ds_read+MFMA on current buffer, then ONE vmcnt(0)+lgkm(0)+barrier per K-step.
// Stage loads fly across the whole compute phase (~400cyc > L2 latency) -> drain ~free.
// WTAIL: blocks >= ngemm do the W2 transpose (fills gemm1's scheduling bubbles).
// =====================================================================================
template<int KDIM, int NDIM, bool DOGELU, bool GATHER, bool WTAIL>
__global__ __launch_bounds__(256, 3) void moe_gemm_kernel(
        const unsigned short* __restrict__ Amat, const unsigned short* __restrict__ WT,
        const float* __restrict__ bias, const int* __restrict__ counts,
        const int* __restrict__ offs, const int* __restrict__ tok_list,
        unsigned short* __restrict__ Out,
        const float* __restrict__ W2, unsigned short* __restrict__ W2T, int ngemm) {
    // A: 2 bufs x 4096 shorts @0; B: 2 bufs x 8192 shorts @8192. 48 KB total.
    __shared__ __align__(16) unsigned short lds[24576];
    int bid = blockIdx.x;
    int tid = threadIdx.x;

    if (WTAIL && bid >= ngemm) {
        // W2 [8][2048][1024] -> W2T [8][1024][2048], runs in gemm1's tail/bubbles
        int b2 = bid - ngemm;
        int e = b2 & 7; int t = b2 >> 3;
        int c0 = (t & 15) * 64, r0 = (t >> 4) * 64;
        unsigned short (*tl)[66] = (unsigned short (*)[66])lds;
        int ci = (tid & 31) * 2, ri = tid >> 5;
        const float* src = W2 + ((size_t)e * HH + r0) * DD + c0;
#pragma unroll
        for (int j = 0; j < 8; ++j) {
            int r = ri + j * 8;
            float2 v = *(const float2*)&src[(size_t)r * DD + ci];
            tl[ci][r] = f2bf(v.x); tl[ci + 1][r] = f2bf(v.y);
        }
        __syncthreads();
        int r2 = (tid & 15) * 4, c2 = tid >> 4;
        unsigned short* dst = W2T + ((size_t)e * DD + c0) * HH + r0;
#pragma unroll
        for (int j = 0; j < 4; ++j) {
            int c = c2 + j * 16;
            ushort4 v = { tl[c][r2], tl[c][r2 + 1], tl[c][r2 + 2], tl[c][r2 + 3] };
            *(ushort4*)&dst[(size_t)c * HH + r2] = v;
        }
        return;
    }

    constexpr int NKT = KDIM / 32;
    constexpr int NNT = NDIM / 256;
    int e = bid & 7;                        // expert -> XCD pin
    int j = bid >> 3;
    int nt = j % NNT, mt = j / NNT;
    int cnt = counts[e];
    int m0 = mt * 128;
    if (m0 >= cnt) return;
    int n0 = nt * 256;
    int base = offs[e];

    int l = tid & 63, w = tid >> 6;

    // staging: src granule-swizzled, LDS linear (involution with read slot)
    int g = (l & 3) ^ ((l >> 3) & 3);
    int ra0 = m0 + w * 32 + (l >> 2);      if (ra0 >= cnt) ra0 = cnt - 1;
    int ra1 = m0 + w * 32 + (l >> 2) + 16; if (ra1 >= cnt) ra1 = cnt - 1;
    size_t gr0 = GATHER ? (size_t)tok_list[e * BT + ra0] : (size_t)(base + ra0);
    size_t gr1 = GATHER ? (size_t)tok_list[e * BT + ra1] : (size_t)(base + ra1);
    const unsigned short* pa0 = Amat + gr0 * KDIM + g * 8;
    const unsigned short* pa1 = Amat + gr1 * KDIM + g * 8;
    const unsigned short* pb[4];
#pragma unroll
    for (int i = 0; i < 4; ++i)
        pb[i] = WT + ((size_t)e * NDIM + n0 + w * 64 + i * 16 + (l >> 2)) * KDIM + g * 8;

    int slot = (l >> 4) ^ ((l >> 1) & 3);
    int rdA = (l & 15) * 32 + slot * 8;                      // + cur*4096 + fm*512
    int rdB = (w * 64 + (l & 15)) * 32 + slot * 8;           // + 8192 + cur*8192 + fn*512

    f32x4 acc[8][4];
#pragma unroll
    for (int i = 0; i < 8; ++i)
#pragma unroll
        for (int q = 0; q < 4; ++q) acc[i][q] = (f32x4){0.f, 0.f, 0.f, 0.f};

#define STAGE(KOF, BUF)                                                           \
    gload16(pa0 + (KOF) * 32, &lds[(BUF) * 4096 + w * 1024]);                     \
    gload16(pa1 + (KOF) * 32, &lds[(BUF) * 4096 + w * 1024 + 512]);               \
    gload16(pb[0] + (KOF) * 32, &lds[8192 + (BUF) * 8192 + w * 2048]);            \
    gload16(pb[1] + (KOF) * 32, &lds[8192 + (BUF) * 8192 + w * 2048 + 512]);      \
    gload16(pb[2] + (KOF) * 32, &lds[8192 + (BUF) * 8192 + w * 2048 + 1024]);     \
    gload16(pb[3] + (KOF) * 32, &lds[8192 + (BUF) * 8192 + w * 2048 + 1536]);

    // prologue: tile0 -> buf0, drain, barrier (tile0 visible to all waves)
    STAGE(0, 0)
    asm volatile("s_waitcnt vmcnt(0)" ::: "memory");
    __builtin_amdgcn_s_barrier();

    for (int kt = 0; kt < NKT; ++kt) {
        int cur = kt & 1;
        // 1) issue next-tile loads FIRST — they fly across the whole compute phase.
        //    WAR-safe: buf cur^1's readers (iter kt-1) consumed data at MFMA issue,
        //    before their barrier entry at end of kt-1.
        int kof = kt + 1; if (kof > NKT - 1) kof = NKT - 1;   // clamped tail (dest never read)
        STAGE(kof, cur ^ 1)

        // 2) compute on current buffer
        int ab = cur * 4096 + rdA;
        int bb = 8192 + cur * 8192 + rdB;
        bf16x8 af[8], bf[4];
#pragma unroll
        for (int f = 0; f < 8; ++f) af[f] = *(const bf16x8*)&lds[ab + f * 512];
#pragma unroll
        for (int f = 0; f < 4; ++f) bf[f] = *(const bf16x8*)&lds[bb + f * 512];
#pragma unroll
        for (int fm = 0; fm < 8; ++fm)
#pragma unroll
            for (int fn = 0; fn < 4; ++fn)   // swapped: D[n][token]
                acc[fm][fn] = __builtin_amdgcn_mfma_f32_16x16x32_bf16(bf[fn], af[fm], acc[fm][fn], 0, 0, 0);

        // 3) single sync point per K-step: own loads landed + own reads drained, barrier
        __builtin_amdgcn_sched_barrier(0);
        asm volatile("s_waitcnt vmcnt(0) lgkmcnt(0)" ::: "memory");
        __builtin_amdgcn_sched_barrier(0);
        __builtin_amdgcn_s_barrier();
        __builtin_amdgcn_sched_barrier(0);
    }
#undef STAGE

    // epilogue: lane holds 4 consecutive n for token col l&15
    const float* be = bias + e * NDIM;
#pragma unroll
    for (int fm = 0; fm < 8; ++fm) {
        int r = m0 + fm * 16 + (l & 15);
        if (r >= cnt) continue;
        unsigned short* orow = Out + (size_t)(base + r) * NDIM;
#pragma unroll
        for (int fn = 0; fn < 4; ++fn) {
            int n = n0 + w * 64 + fn * 16 + (l >> 4) * 4;
            float4 bb4 = *(const float4*)&be[n];
            f32x4 a = acc[fm][fn];
            float v0 = a[0] + bb4.x, v1 = a[1] + bb4.y;
            float v2 = a[2] + bb4.z, v3 = a[3] + bb4.w;
            if (DOGELU) {
                v0 = gelu_fast(v0); v1 = gelu_fast(v1);
                v2 = gelu_fast(v2); v3 = gelu_fast(v3);
            }
            ushort4 pk = { f2bf(v0), f2bf(v1), f2bf(v2), f2bf(v3) };
            *(ushort4*)&orow[n] = pk;
        }
    }
}

// ---------------- combine (+ fused aux): out[t] = w1*y[row1] + (1-w1)*y[row2] ----------------
__global__ __launch_bounds__(256) void combine_kernel(
        const unsigned short* __restrict__ ybuf, const int* __restrict__ offs,
        const int* __restrict__ tk_pack, const float* __restrict__ tk_w,
        const int* __restrict__ tk_pos, const float* __restrict__ ssq,
        float* __restrict__ out) {
    if (blockIdx.x == BT / 2) {
        __shared__ float red[4];
        float s = 0.f;
        for (int i = threadIdx.x; i < BT; i += 256) s += ssq[i];
#pragma unroll
        for (int off = 32; off; off >>= 1) s += __shfl_xor(s, off, 64);
        if ((threadIdx.x & 63) == 0) red[threadIdx.x >> 6] = s;
        __syncthreads();
        if (threadIdx.x == 0)
            out[(size_t)BT * DD] = (red[0] + red[1] + red[2] + red[3]) * (float)EE / (float)BT;
        return;
    }
    int tid = threadIdx.x;
    int t  = blockIdx.x * 2 + (tid >> 7);
    int lt = tid & 127;
    int pk  = tk_pack[t];
    int pos = tk_pos[t];
    float w1 = tk_w[t], w2 = 1.f - w1;
    int r1 = offs[pk & 15] + (pos & 0xffff);
    int r2 = offs[pk >> 4] + (pos >> 16);
    ushort4 a0 = ((const ushort4*)(ybuf + (size_t)r1 * DD))[lt * 2];
    ushort4 a1 = ((const ushort4*)(ybuf + (size_t)r1 * DD))[lt * 2 + 1];
    ushort4 b0 = ((const ushort4*)(ybuf + (size_t)r2 * DD))[lt * 2];
    ushort4 b1 = ((const ushort4*)(ybuf + (size_t)r2 * DD))[lt * 2 + 1];
    float4 o0 = { w1 * bf2f(a0.x) + w2 * bf2f(b0.x), w1 * bf2f(a0.y) + w2 * bf2f(b0.y),
                  w1 * bf2f(a0.z) + w2 * bf2f(b0.z), w1 * bf2f(a0.w) + w2 * bf2f(b0.w) };
    float4 o1 = { w1 * bf2f(a1.x) + w2 * bf2f(b1.x), w1 * bf2f(a1.y) + w2 * bf2f(b1.y),
                  w1 * bf2f(a1.z) + w2 * bf2f(b1.z), w1 * bf2f(a1.w) + w2 * bf2f(b1.w) };
    float4* orow = (float4*)(out + (size_t)t * DD);
    orow[lt * 2]     = o0;
    orow[lt * 2 + 1] = o1;
}

extern "C" void kernel_launch(void* const* d_in, const int* in_sizes, int n_in,
                              void* d_out, int out_size, void* d_ws, size_t ws_size,
                              hipStream_t stream) {
    const float* x  = (const float*)d_in[0];
    const float* Wg = (const float*)d_in[1];
    const float* bg = (const float*)d_in[2];
    const float* W1 = (const float*)d_in[3];
    const float* b1 = (const float*)d_in[4];
    const float* W2 = (const float*)d_in[5];
    const float* b2 = (const float*)d_in[6];
    float* out = (float*)d_out;

    char* wsb = (char*)d_ws;
    int*   counts  = (int*)wsb;                         // 0 .. 32
    int*   sdone   = (int*)(wsb + 32);                  // 32 .. 36
    int*   offs    = (int*)(wsb + 64);                  // 64 .. 100
    int*   tok     = (int*)(wsb + 256);                 // -> 262400
    float* ssq     = (float*)(wsb + 262400);            // -> 295168
    int*   tk_pack = (int*)(wsb + 295168);              // -> 327936
    float* tk_w    = (float*)(wsb + 327936);            // -> 360704
    int*   tk_pos  = (int*)(wsb + 360704);              // -> 393472
    unsigned short* xbf  = (unsigned short*)(wsb + 393472);      // 16 MB -> 17170688
    unsigned short* W1T  = (unsigned short*)(wsb + 17170688);    // 32 MB -> 50725120
    unsigned short* W2T  = (unsigned short*)(wsb + 50725120);    // 32 MB -> 84279552
    unsigned short* hbuf = (unsigned short*)(wsb + 84279552);    // 64 MB -> 151388416
    // ybuf (33.5 MB bf16) overlays xbf+W1T — both dead once gemm1 has run
    unsigned short* ybuf = (unsigned short*)(wsb + 393472);

    hipMemsetAsync(wsb, 0, 64, stream);                 // counts + sdone

    prep_kernel<<<BT / 4 + 4096, 256, 0, stream>>>(x, Wg, bg, W1,
                                                   tk_pack, tk_w, ssq, xbf, W1T);
    scatter_kernel<<<BT / 256, 256, 0, stream>>>(tk_pack, counts, sdone, tok, tk_pos, offs);
    // gemm1 (4096 gemm blocks) + W2-transpose tail (4096 blocks in gemm1's bubbles)
    moe_gemm_kernel<DD, HH, true, true, true><<<8192, 256, 0, stream>>>(
        xbf, W1T, b1, counts, offs, tok, hbuf, W2, W2T, 4096);
    moe_gemm_kernel<HH, DD, false, false, false><<<2048, 256, 0, stream>>>(
        hbuf, W2T, b2, counts, offs, tok, ybuf, nullptr, nullptr, 2048);
    combine_kernel<<<BT / 2 + 1, 256, 0, stream>>>(ybuf, offs, tk_pack, tk_w, tk_pos, ssq, out);
}